// Round 17
// baseline (675.594 us; speedup 1.0000x reference)
//
#include <hip/hip_runtime.h>
#include <cstdint>
#include <cstddef>

namespace {

constexpr int Bb = 8;
constexpr int Nn = 2048;
constexpr int Dd = 1024;
constexpr int NT = 64;  // kv tiles of 32

typedef _Float16 half8 __attribute__((ext_vector_type(8)));
typedef float f32x2v __attribute__((ext_vector_type(2)));
typedef float f32x4v __attribute__((ext_vector_type(4)));
typedef float f32x16v __attribute__((ext_vector_type(16)));
typedef unsigned int v2u __attribute__((ext_vector_type(2)));
typedef unsigned int v4u __attribute__((ext_vector_type(4)));

__device__ __forceinline__ float fast_exp2(float x) {
  float r;
  asm("v_exp_f32 %0, %1\n\ts_nop 1" : "=v"(r) : "v"(x));
  return r;
}

// pack two f32 -> one u32 of 2x fp16 (RTZ); src0 -> low 16 bits
__device__ __forceinline__ unsigned cvt2(float a, float b) {
  return __builtin_bit_cast(unsigned, __builtin_amdgcn_cvt_pkrtz(a, b));
}

// DPP lane exchange (VALU pipe), CTRL compile-time.
template <int CTRL>
__device__ __forceinline__ float dpp_f(float v) {
  return __builtin_bit_cast(
      float, __builtin_amdgcn_update_dpp(0, __builtin_bit_cast(int, v), CTRL,
                                         0xF, 0xF, true));
}
// reduce over a 16-lane row: quad xor1, xor2, then row_ror 4, 8.
__device__ __forceinline__ float red16_max(float v) {
  v = fmaxf(v, dpp_f<0xB1>(v));
  v = fmaxf(v, dpp_f<0x4E>(v));
  v = fmaxf(v, dpp_f<0x124>(v));
  v = fmaxf(v, dpp_f<0x128>(v));
  return v;
}
__device__ __forceinline__ float red16_add(float v) {
  v = v + dpp_f<0xB1>(v);
  v = v + dpp_f<0x4E>(v);
  v = v + dpp_f<0x124>(v);
  v = v + dpp_f<0x128>(v);
  return v;
}

__device__ __forceinline__ void barrier_lgkm() {
  asm volatile("s_waitcnt lgkmcnt(0)" ::: "memory");
  __builtin_amdgcn_s_barrier();
  __builtin_amdgcn_sched_barrier(0);
}
__device__ __forceinline__ void barrier_plain() {
  __builtin_amdgcn_s_barrier();
  __builtin_amdgcn_sched_barrier(0);
}

// fp32 -> packed fp16 stream (same element order, 2B/elem)
__global__ void convf16(const float* __restrict__ in, v4u* __restrict__ out) {
  const int n8 = Bb * Nn * Dd / 8;
  int i = blockIdx.x * blockDim.x + threadIdx.x;
  const int stride = gridDim.x * blockDim.x;
  const f32x4v* in4 = (const f32x4v*)in;
  for (; i < n8; i += stride) {
    f32x4v a = in4[2 * i], b = in4[2 * i + 1];
    v4u p;
    p[0] = cvt2(a[0], a[1]);
    p[1] = cvt2(a[2], a[3]);
    p[2] = cvt2(b[0], b[1]);
    p[3] = cvt2(b[2], b[3]);
    out[i] = p;
  }
}

template <int WS>
__device__ __forceinline__ v4u ld8h(const float* f32p, const v4u* h16p) {
  if constexpr (WS) {
    return *h16p;
  } else {
    f32x4v a = *(const f32x4v*)f32p;
    f32x4v b = *(const f32x4v*)(f32p + 4);
    v4u p;
    p[0] = cvt2(a[0], a[1]);
    p[1] = cvt2(a[2], a[3]);
    p[2] = cvt2(b[0], b[1]);
    p[3] = cvt2(b[2], b[3]);
    return p;
  }
}

// Flash attention fwd (no scale), K == V == Y. 512 threads = 8 waves:
// wave = (kvf in 0..1) x (ds in 0..3, 256-d slice). QB=32, KVB=32.
// Two-tile pipeline, 2 barriers/tile, double ybuf + double Pb:
//  ph A(t): pa/flags(t-1) rd | ISSUE_TR(t-1) | 16 S-MFMA(t) | LOADY(t+1) |
//           pscr wr | lgkm0 | rescale | 8 PV-MFMA(t-1)            [B1 plain]
//  ph B(t): all-wave softmax(t) -> Pb[t&1]/sscale/flags |
//           STAGE(s -> ybuf[(t+1)&1])                             [B2 lgkm]
template <int WS>
__global__ __launch_bounds__(512, 2) void flash_fwd(
    const float* __restrict__ Qf, const float* __restrict__ Yf,
    const v4u* __restrict__ Qw, const v4u* __restrict__ Yw,
    float* __restrict__ Om) {
  // per-slot tr-window layout:
  // addr(kv,d) = (kv>>2)*8192 + (d>>4)*128 + (kv&3)*32 + (d&15)*2
  __shared__ __attribute__((aligned(128))) char ybuf[2][65536];
  __shared__ __attribute__((aligned(16))) float pscr2[4][32][36];
  __shared__ __attribute__((aligned(16))) char Pb[2][2048];  // [slot][oct][q]
  __shared__ float sscale[32];
  __shared__ float sinvl[32];
  __shared__ __attribute__((aligned(16))) int sflag8[8];

  const int tid = (int)threadIdx.x;
  const int w = tid >> 6, l = tid & 63;
  const int lm = l & 15, g = (l >> 4) & 3, g2 = (l >> 5) & 1, l31 = l & 31;
  const int kvf = w >> 2, ds = w & 3;
  const int bid = (int)blockIdx.x, batch = bid & 7, row0 = (bid >> 3) * 32;
  const size_t bY = (size_t)batch * Nn;

  // ---- Q fragments (B-operand): lane(lm,g): q = qh*16+lm,
  // d = ds*256 + ks*32 + g*8 + i   (ks = 0..7)
  v4u qreg[2][8];
#pragma unroll
  for (int qh = 0; qh < 2; ++qh)
#pragma unroll
    for (int ks = 0; ks < 8; ++ks) {
      const int rr = row0 + qh * 16 + lm;
      const int dd_ = ds * 256 + ks * 32 + g * 8;
      qreg[qh][ks] = ld8h<WS>(Qf + (size_t)(bY + rr) * Dd + dd_,
                              Qw + (size_t)(bY + rr) * 128 + (dd_ >> 3));
    }

#define LOADY(dst, t_)                                                        \
  do {                                                                        \
    const int rr_ = (t_)*32 + kvf * 16 + lm;                                  \
    _Pragma("unroll") for (int ks = 0; ks < 8; ++ks) {                        \
      const int dd_ = ds * 256 + ks * 32 + g * 8;                             \
      dst[ks] = ld8h<WS>(Yf + (size_t)(bY + rr_) * Dd + dd_,                  \
                         Yw + (size_t)(bY + rr_) * 128 + (dd_ >> 3));         \
    }                                                                         \
  } while (0)

  // staging write: lane(lm,g) kv=kvf*16+lm, d=ds*256+ks*32+g*8 (16B half-row)
  const unsigned sbase =
      (unsigned)((kvf * 4 + (lm >> 2)) * 8192 + (ds * 16 + (g >> 1)) * 128 +
                 (lm & 3) * 32 + (g & 1) * 16);
#define STAGE_WR(SRC, BASE)                                                   \
  do {                                                                        \
    _Pragma("unroll") for (int ks = 0; ks < 8; ++ks)                          \
        *(v4u*)((BASE) + sbase + ks * 256) = SRC[ks];                         \
  } while (0)

#define ISSUE_TR(DST, TRBASE)                                                 \
  do {                                                                        \
    _Pragma("unroll") for (int kb = 0; kb < 2; ++kb)                          \
        _Pragma("unroll") for (int df = 0; df < 4; ++df) {                    \
      const unsigned wb =                                                     \
          (TRBASE) + (unsigned)((kb * 4 + g2 * 2) * 8192 +                    \
                                ((w * 4 + df) * 2 + (l31 >> 4)) * 128 +       \
                                (l31 & 15) * 8);                              \
      asm volatile("ds_read_b64_tr_b16 %0, %1"                                \
                   : "=v"(DST[kb * 8 + df * 2])                               \
                   : "v"(wb));                                                \
      asm volatile("ds_read_b64_tr_b16 %0, %1"                                \
                   : "=v"(DST[kb * 8 + df * 2 + 1])                           \
                   : "v"(wb + 8192u));                                        \
    }                                                                         \
  } while (0)

// S-MFMA block for tile in s, accumulators acc0/acc1, then pscr store.
#define S_BLOCK()                                                             \
  do {                                                                        \
    _Pragma("unroll") for (int ks = 0; ks < 8; ++ks) {                        \
      half8 av = __builtin_bit_cast(half8, s[ks]);                            \
      acc0 = __builtin_amdgcn_mfma_f32_16x16x32_f16(                          \
          av, __builtin_bit_cast(half8, qreg[0][ks]), acc0, 0, 0, 0);         \
      acc1 = __builtin_amdgcn_mfma_f32_16x16x32_f16(                          \
          av, __builtin_bit_cast(half8, qreg[1][ks]), acc1, 0, 0, 0);         \
    }                                                                         \
  } while (0)

// all-wave softmax for tile t; writes P into PBW, sscale, sflag8.
#define SOFTMAX(PBW)                                                          \
  do {                                                                        \
    const int rq = 4 * w + (l >> 4); /* q row */                              \
    const int c = l & 15;            /* kv pair (kv = 2c, 2c+1) */            \
    float s0 = 0.f, s1 = 0.f;                                                 \
    _Pragma("unroll") for (int sl = 0; sl < 4; ++sl) {                        \
      f32x2v p_ = *(const f32x2v*)&pscr2[sl][rq][2 * c];                      \
      s0 += p_[0];                                                            \
      s1 += p_[1];                                                            \
    }                                                                         \
    float pm = red16_max(fmaxf(s0, s1));                                      \
    bool defer = (pm <= m_run + 8.0f);                                        \
    bool allw = (bool)__all((int)defer);                                      \
    float scale = 1.0f;                                                       \
    if (!allw) {                                                              \
      float mn = fmaxf(m_run, pm);                                            \
      scale = fast_exp2((m_run - mn) * L2E);                                  \
      m_run = mn;                                                             \
    }                                                                         \
    float e0 = fast_exp2((s0 - m_run) * L2E);                                 \
    float e1 = fast_exp2((s1 - m_run) * L2E);                                 \
    float ps = red16_add(e0 + e1);                                            \
    l_run = l_run * scale + ps;                                               \
    *(unsigned*)((PBW) + (c >> 2) * 512 + rq * 16 + (c & 3) * 4) =            \
        cvt2(e0, e1);                                                         \
    if (c == 0) sscale[rq] = scale;                                           \
    if (l == 0) sflag8[w] = allw ? 0 : 1;                                     \
  } while (0)

// rescale + PV-MFMAs using pa0/pa1 + trr (after lgkm0).
#define PV_MFMA()                                                             \
  do {                                                                        \
    if (f0[0] | f0[1] | f0[2] | f0[3] | f1[0] | f1[1] | f1[2] | f1[3]) {      \
      _Pragma("unroll") for (int df = 0; df < 4; ++df)                        \
          _Pragma("unroll") for (int r = 0; r < 16; ++r) {                    \
        const int q_ = (r & 3) + 8 * (r >> 2) + 4 * g2;                       \
        Oacc[df][r] *= sscale[q_];                                            \
      }                                                                       \
    }                                                                         \
    _Pragma("unroll") for (int kb = 0; kb < 2; ++kb)                          \
        _Pragma("unroll") for (int df = 0; df < 4; ++df) {                    \
      v4u bu;                                                                 \
      bu[0] = trr[kb * 8 + df * 2][0];                                        \
      bu[1] = trr[kb * 8 + df * 2][1];                                        \
      bu[2] = trr[kb * 8 + df * 2 + 1][0];                                    \
      bu[3] = trr[kb * 8 + df * 2 + 1][1];                                    \
      Oacc[df] = __builtin_amdgcn_mfma_f32_32x32x16_f16(                      \
          kb ? pa1 : pa0, __builtin_bit_cast(half8, bu), Oacc[df], 0, 0, 0);  \
    }                                                                         \
  } while (0)

  char* const yb0 = &ybuf[0][0];
  const unsigned ylds = (unsigned)(uintptr_t)yb0;
  constexpr float L2E = 1.44269504088896f;

  v4u s[8];
  LOADY(s, 0);
  STAGE_WR(s, yb0);  // tile 0 -> slot 0

  f32x16v Oacc[4];
#pragma unroll
  for (int i = 0; i < 4; ++i)
#pragma unroll
    for (int j = 0; j < 16; ++j) Oacc[i][j] = 0.0f;

  float m_run = -__builtin_inff();
  float l_run = 0.0f;

  __syncthreads();

  // ---- peeled tile 0 (no PV)
  {
    f32x4v acc0 = {0.f, 0.f, 0.f, 0.f}, acc1 = {0.f, 0.f, 0.f, 0.f};
    S_BLOCK();
    LOADY(s, 1);
    *(f32x4v*)&pscr2[ds][lm][kvf * 16 + g * 4] = acc0;
    *(f32x4v*)&pscr2[ds][16 + lm][kvf * 16 + g * 4] = acc1;
    barrier_lgkm();  // B1(0)
    SOFTMAX(&Pb[0][0]);
    STAGE_WR(s, yb0 + 65536);  // tile 1 -> slot 1
    barrier_lgkm();  // B2(0)
  }

  // ---- main loop: tiles 1..63; PV(t-1) in phase A
  for (int t = 1; t < NT; ++t) {
    const unsigned trbase = ylds + (unsigned)(((t - 1) & 1) * 65536);
    char* const ybn = yb0 + (((t + 1) & 1) * 65536);
    const char* pbp = &Pb[(t - 1) & 1][0];
    char* const pbw = &Pb[t & 1][0];

    // phase A
    half8 pa0 = *(const half8*)(pbp + g2 * 512 + l31 * 16);
    half8 pa1 = *(const half8*)(pbp + (2 + g2) * 512 + l31 * 16);
    v4u f0 = *(const v4u*)&sflag8[0];
    v4u f1 = *(const v4u*)&sflag8[4];
    v2u trr[16];
    ISSUE_TR(trr, trbase);
    f32x4v acc0 = {0.f, 0.f, 0.f, 0.f}, acc1 = {0.f, 0.f, 0.f, 0.f};
    S_BLOCK();
    LOADY(s, (t + 1) & 63);
    *(f32x4v*)&pscr2[ds][lm][kvf * 16 + g * 4] = acc0;
    *(f32x4v*)&pscr2[ds][16 + lm][kvf * 16 + g * 4] = acc1;
    asm volatile("s_waitcnt lgkmcnt(0)" ::: "memory");
    __builtin_amdgcn_sched_barrier(0);
    PV_MFMA();
    barrier_plain();  // B1(t): pscr visible; ybuf slot free for stage

    // phase B
    SOFTMAX(pbw);
    STAGE_WR(s, ybn);  // tile t+1 -> slot (t+1)&1
    barrier_lgkm();    // B2(t): P/scales/flags/ybuf(t+1) visible
  }

  // ---- final PV (tile 63)
  {
    const unsigned trbase = ylds + 65536u;  // slot 1
    const char* pbp = &Pb[1][0];
    half8 pa0 = *(const half8*)(pbp + g2 * 512 + l31 * 16);
    half8 pa1 = *(const half8*)(pbp + (2 + g2) * 512 + l31 * 16);
    v4u f0 = *(const v4u*)&sflag8[0];
    v4u f1 = *(const v4u*)&sflag8[4];
    v2u trr[16];
    ISSUE_TR(trr, trbase);
    asm volatile("s_waitcnt lgkmcnt(0)" ::: "memory");
    __builtin_amdgcn_sched_barrier(0);
    PV_MFMA();
  }

  // ---- epilogue
  if ((l & 15) == 0) sinvl[4 * w + (l >> 4)] = 1.0f / l_run;
  __syncthreads();
#pragma unroll
  for (int df = 0; df < 4; ++df)
#pragma unroll
    for (int r = 0; r < 16; ++r) {
      const int q_ = (r & 3) + 8 * (r >> 2) + 4 * g2;
      const float inv = sinvl[q_];
      Om[(size_t)(bY + row0 + q_) * Dd + (w * 4 + df) * 32 + l31] =
          Oacc[df][r] * inv;
    }
#undef PV_MFMA
#undef SOFTMAX
#undef S_BLOCK
#undef ISSUE_TR
#undef STAGE_WR
#undef LOADY
}

}  // namespace

extern "C" void kernel_launch(void* const* d_in, const int* in_sizes, int n_in,
                              void* d_out, int out_size, void* d_ws,
                              size_t ws_size, hipStream_t stream) {
  (void)in_sizes; (void)n_in; (void)out_size;
  const float* x = (const float*)d_in[0];
  const float* y = (const float*)d_in[1];
  float* A = (float*)d_out;
  float* Bo = A + (size_t)Bb * Nn * Dd;
  const size_t halfws = (size_t)Bb * Nn * Dd * 2;  // 32 MiB per matrix
  dim3 fg(512), fb(512);
  if (d_ws != nullptr && ws_size >= 2 * halfws) {
    v4u* Xw = (v4u*)d_ws;
    v4u* Yw = (v4u*)((char*)d_ws + halfws);
    hipLaunchKernelGGL(convf16, dim3(2048), dim3(256), 0, stream, x, Xw);
    hipLaunchKernelGGL(convf16, dim3(2048), dim3(256), 0, stream, y, Yw);
    hipLaunchKernelGGL(flash_fwd<1>, fg, fb, 0, stream, x, y, Xw, Yw, A);
    hipLaunchKernelGGL(flash_fwd<1>, fg, fb, 0, stream, y, x, Yw, Xw, Bo);
  } else {
    hipLaunchKernelGGL(flash_fwd<0>, fg, fb, 0, stream, x, y, (const v4u*)x,
                       (const v4u*)y, A);
    hipLaunchKernelGGL(flash_fwd<0>, fg, fb, 0, stream, y, x, (const v4u*)y,
                       (const v4u*)x, Bo);
  }
}

// Round 18
// 633.144 us; speedup vs baseline: 1.0670x; 1.0670x over previous
//
#include <hip/hip_runtime.h>
#include <cstdint>
#include <cstddef>

namespace {

constexpr int Bb = 8;
constexpr int Nn = 2048;
constexpr int Dd = 1024;
constexpr int NT = 64;  // kv tiles of 32

typedef _Float16 half8 __attribute__((ext_vector_type(8)));
typedef float f32x2v __attribute__((ext_vector_type(2)));
typedef float f32x4v __attribute__((ext_vector_type(4)));
typedef float f32x16v __attribute__((ext_vector_type(16)));
typedef unsigned int v2u __attribute__((ext_vector_type(2)));
typedef unsigned int v4u __attribute__((ext_vector_type(4)));

__device__ __forceinline__ float fast_exp2(float x) {
  float r;
  asm("v_exp_f32 %0, %1\n\ts_nop 1" : "=v"(r) : "v"(x));
  return r;
}

__device__ __forceinline__ unsigned cvt2(float a, float b) {
  return __builtin_bit_cast(unsigned, __builtin_amdgcn_cvt_pkrtz(a, b));
}

template <int CTRL>
__device__ __forceinline__ float dpp_f(float v) {
  return __builtin_bit_cast(
      float, __builtin_amdgcn_update_dpp(0, __builtin_bit_cast(int, v), CTRL,
                                         0xF, 0xF, true));
}
__device__ __forceinline__ float red16_max(float v) {
  v = fmaxf(v, dpp_f<0xB1>(v));
  v = fmaxf(v, dpp_f<0x4E>(v));
  v = fmaxf(v, dpp_f<0x124>(v));
  v = fmaxf(v, dpp_f<0x128>(v));
  return v;
}
__device__ __forceinline__ float red16_add(float v) {
  v = v + dpp_f<0xB1>(v);
  v = v + dpp_f<0x4E>(v);
  v = v + dpp_f<0x124>(v);
  v = v + dpp_f<0x128>(v);
  return v;
}

__device__ __forceinline__ void barrier_lgkm() {
  asm volatile("s_waitcnt lgkmcnt(0)" ::: "memory");
  __builtin_amdgcn_s_barrier();
  __builtin_amdgcn_sched_barrier(0);
}
__device__ __forceinline__ void barrier_plain() {
  __builtin_amdgcn_s_barrier();
  __builtin_amdgcn_sched_barrier(0);
}

// fp32 -> packed fp16 stream (same element order, 2B/elem)
__global__ void convf16(const float* __restrict__ in, v4u* __restrict__ out) {
  const int n8 = Bb * Nn * Dd / 8;
  int i = blockIdx.x * blockDim.x + threadIdx.x;
  const int stride = gridDim.x * blockDim.x;
  const f32x4v* in4 = (const f32x4v*)in;
  for (; i < n8; i += stride) {
    f32x4v a = in4[2 * i], b = in4[2 * i + 1];
    v4u p;
    p[0] = cvt2(a[0], a[1]);
    p[1] = cvt2(a[2], a[3]);
    p[2] = cvt2(b[0], b[1]);
    p[3] = cvt2(b[2], b[3]);
    out[i] = p;
  }
}

template <int WS>
__device__ __forceinline__ v4u ld8h(const float* f32p, const v4u* h16p) {
  if constexpr (WS) {
    return *h16p;
  } else {
    f32x4v a = *(const f32x4v*)f32p;
    f32x4v b = *(const f32x4v*)(f32p + 4);
    v4u p;
    p[0] = cvt2(a[0], a[1]);
    p[1] = cvt2(a[2], a[3]);
    p[2] = cvt2(b[0], b[1]);
    p[3] = cvt2(b[2], b[3]);
    return p;
  }
}

// Flash attention fwd (no scale), K == V == Y. 512 threads = 8 waves:
// wave = (kvf in 0..1) x (ds in 0..3, 256-d slice). QB=32, KVB=32.
// Champion schedule (3 barriers, PV same-tile); WS=1 stages Y via
// global_load_lds directly into the tr-window layout (dest = base+16*lane
// matches the layout with per-lane source row=w*4+((l>>1)&3),
// d=j*128+(l>>3)*16+(l&1)*8); S-fragments read back via ds_read_b128.
template <int WS>
__global__ __launch_bounds__(512, 2) void flash_fwd(
    const float* __restrict__ Qf, const float* __restrict__ Yf,
    const v4u* __restrict__ Qw, const v4u* __restrict__ Yw,
    float* __restrict__ Om) {
  // per-slot tr-window layout:
  // addr(kv,d) = (kv>>2)*8192 + (d>>4)*128 + (kv&3)*32 + (d&15)*2
  __shared__ __attribute__((aligned(128))) char ybuf[2][65536];
  __shared__ __attribute__((aligned(16))) float pscr2[4][32][36];
  __shared__ __attribute__((aligned(16))) char Pb[2048];  // [oct][q] 16B
  __shared__ float sscale[32];
  __shared__ float sinvl[32];
  __shared__ __attribute__((aligned(16))) int sflag8[8];

  const int tid = (int)threadIdx.x;
  const int w = tid >> 6, l = tid & 63;
  const int lm = l & 15, g = (l >> 4) & 3, g2 = (l >> 5) & 1, l31 = l & 31;
  const int kvf = w >> 2, ds = w & 3;
  const int bid = (int)blockIdx.x, batch = bid & 7, row0 = (bid >> 3) * 32;
  const size_t bY = (size_t)batch * Nn;

  // ---- Q fragments (B-operand): lane(lm,g): q = qh*16+lm,
  // d = ds*256 + ks*32 + g*8 + i   (ks = 0..7)
  v4u qreg[2][8];
#pragma unroll
  for (int qh = 0; qh < 2; ++qh)
#pragma unroll
    for (int ks = 0; ks < 8; ++ks) {
      const int rr = row0 + qh * 16 + lm;
      const int dd_ = ds * 256 + ks * 32 + g * 8;
      qreg[qh][ks] = ld8h<WS>(Qf + (size_t)(bY + rr) * Dd + dd_,
                              Qw + (size_t)(bY + rr) * 128 + (dd_ >> 3));
    }

  // S-fragment read base (= old stage-write base), + ks*256
  const unsigned sbase =
      (unsigned)((kvf * 4 + (lm >> 2)) * 8192 + (ds * 16 + (g >> 1)) * 128 +
                 (lm & 3) * 32 + (g & 1) * 16);

  // ---- WS=1: DMA staging. Wave w covers kv-quad w; 8 chunks of 128 d.
#define DMA_STAGE(t_, SLOT)                                                   \
  do {                                                                        \
    const int rl_ = (t_)*32 + (w << 2) + ((l >> 1) & 3);                      \
    const v4u* gp_ = Yw + (size_t)(bY + rl_) * 128 + ((l >> 3) << 1) + (l & 1); \
    char* lp_ = &ybuf[(SLOT)][0] + w * 8192;                                  \
    _Pragma("unroll") for (int j = 0; j < 8; ++j) {                           \
      __builtin_amdgcn_global_load_lds(                                       \
          (const __attribute__((address_space(1))) unsigned*)(const void*)(gp_ + j * 16), \
          (__attribute__((address_space(3))) unsigned*)(void*)(lp_ + j * 1024), \
          16, 0, 0);                                                          \
    }                                                                         \
  } while (0)

  // ---- WS=0: reg staging (fallback)
#define LOADY(dst, t_)                                                        \
  do {                                                                        \
    const int rr_ = (t_)*32 + kvf * 16 + lm;                                  \
    _Pragma("unroll") for (int ks = 0; ks < 8; ++ks) {                        \
      const int dd_ = ds * 256 + ks * 32 + g * 8;                             \
      dst[ks] = ld8h<WS>(Yf + (size_t)(bY + rr_) * Dd + dd_,                  \
                         Yw + (size_t)(bY + rr_) * 128 + (dd_ >> 3));         \
    }                                                                         \
  } while (0)
#define STAGE_WR(SRC, BASE)                                                   \
  do {                                                                        \
    _Pragma("unroll") for (int ks = 0; ks < 8; ++ks)                          \
        *(v4u*)((BASE) + sbase + ks * 256) = SRC[ks];                         \
  } while (0)

  v4u s[8];  // only used when WS == 0
  if constexpr (WS) {
    DMA_STAGE(0, 0);
    asm volatile("s_waitcnt vmcnt(0)" ::: "memory");
  } else {
    LOADY(s, 0);
    STAGE_WR(s, &ybuf[0][0]);
    LOADY(s, 1);
  }

  f32x16v Oacc[4];
#pragma unroll
  for (int i = 0; i < 4; ++i)
#pragma unroll
    for (int j = 0; j < 16; ++j) Oacc[i][j] = 0.0f;

  float m_run = -__builtin_inff();
  float l_run = 0.0f;
  const unsigned ylds = (unsigned)(uintptr_t)&ybuf[0][0];
  constexpr float L2E = 1.44269504088896f;

  v2u trr[16];

#define ISSUE_TR(TRBASE)                                                      \
  do {                                                                        \
    _Pragma("unroll") for (int kb = 0; kb < 2; ++kb)                          \
        _Pragma("unroll") for (int df = 0; df < 4; ++df) {                    \
      const unsigned wb =                                                     \
          (TRBASE) + (unsigned)((kb * 4 + g2 * 2) * 8192 +                    \
                                ((w * 4 + df) * 2 + (l31 >> 4)) * 128 +       \
                                (l31 & 15) * 8);                              \
      asm volatile("ds_read_b64_tr_b16 %0, %1"                                \
                   : "=v"(trr[kb * 8 + df * 2])                               \
                   : "v"(wb));                                                \
      asm volatile("ds_read_b64_tr_b16 %0, %1"                                \
                   : "=v"(trr[kb * 8 + df * 2 + 1])                           \
                   : "v"(wb + 8192u));                                        \
    }                                                                         \
  } while (0)

  __syncthreads();

  for (int t = 0; t < NT; ++t) {
    const char* ybc = &ybuf[t & 1][0];
    const unsigned ytr = ylds + (unsigned)((t & 1) * 65536);

    // ---- phase A: issue next-tile staging, S MFMAs (4 chains), pscr wr
    if constexpr (WS) DMA_STAGE((t + 1) & 63, (t + 1) & 1);
    f32x4v a0a = {0.f, 0.f, 0.f, 0.f}, a0b = {0.f, 0.f, 0.f, 0.f};
    f32x4v a1a = {0.f, 0.f, 0.f, 0.f}, a1b = {0.f, 0.f, 0.f, 0.f};
#pragma unroll
    for (int ks = 0; ks < 8; ++ks) {
      half8 av;
      if constexpr (WS) {
        av = *(const half8*)(ybc + sbase + ks * 256);
      } else {
        av = __builtin_bit_cast(half8, s[ks]);
      }
      if (ks < 4) {
        a0a = __builtin_amdgcn_mfma_f32_16x16x32_f16(
            av, __builtin_bit_cast(half8, qreg[0][ks]), a0a, 0, 0, 0);
        a1a = __builtin_amdgcn_mfma_f32_16x16x32_f16(
            av, __builtin_bit_cast(half8, qreg[1][ks]), a1a, 0, 0, 0);
      } else {
        a0b = __builtin_amdgcn_mfma_f32_16x16x32_f16(
            av, __builtin_bit_cast(half8, qreg[0][ks]), a0b, 0, 0, 0);
        a1b = __builtin_amdgcn_mfma_f32_16x16x32_f16(
            av, __builtin_bit_cast(half8, qreg[1][ks]), a1b, 0, 0, 0);
      }
    }
    f32x4v acc0 = a0a + a0b, acc1 = a1a + a1b;
    *(f32x4v*)&pscr2[ds][lm][kvf * 16 + g * 4] = acc0;
    *(f32x4v*)&pscr2[ds][16 + lm][kvf * 16 + g * 4] = acc1;
    barrier_lgkm();  // B1: partials visible

    // ---- phase B: all-wave softmax (own 4 q-rows) + tr issue
    {
      const int rq = 4 * w + (l >> 4);
      const int c = l & 15;
      float s0 = 0.f, s1 = 0.f;
#pragma unroll
      for (int sl = 0; sl < 4; ++sl) {
        f32x2v p_ = *(const f32x2v*)&pscr2[sl][rq][2 * c];
        s0 += p_[0];
        s1 += p_[1];
      }
      float pm = red16_max(fmaxf(s0, s1));
      bool defer = (pm <= m_run + 8.0f);
      bool allw = (bool)__all((int)defer);
      float scale = 1.0f;
      if (!allw) {
        float mn = fmaxf(m_run, pm);
        scale = fast_exp2((m_run - mn) * L2E);
        m_run = mn;
      }
      float e0 = fast_exp2((s0 - m_run) * L2E);
      float e1 = fast_exp2((s1 - m_run) * L2E);
      float ps = red16_add(e0 + e1);
      l_run = l_run * scale + ps;
      *(unsigned*)(Pb + (c >> 2) * 512 + rq * 16 + (c & 3) * 4) = cvt2(e0, e1);
      if (c == 0) sscale[rq] = scale;
      if (l == 0) sflag8[w] = allw ? 0 : 1;
    }
    ISSUE_TR(ytr);
    barrier_lgkm();  // B2: P + stats visible; tr data in regs

    // ---- phase C: PV
    half8 pa0 = *(const half8*)(Pb + g2 * 512 + l31 * 16);
    half8 pa1 = *(const half8*)(Pb + (2 + g2) * 512 + l31 * 16);
    v4u f0 = *(const v4u*)&sflag8[0];
    v4u f1 = *(const v4u*)&sflag8[4];
    if (f0[0] | f0[1] | f0[2] | f0[3] | f1[0] | f1[1] | f1[2] | f1[3]) {
#pragma unroll
      for (int df = 0; df < 4; ++df)
#pragma unroll
        for (int r = 0; r < 16; ++r) {
          const int q_ = (r & 3) + 8 * (r >> 2) + 4 * g2;
          Oacc[df][r] *= sscale[q_];
        }
    }
    asm volatile("s_waitcnt lgkmcnt(0)" ::: "memory");
    __builtin_amdgcn_sched_barrier(0);
#pragma unroll
    for (int kb = 0; kb < 2; ++kb)
#pragma unroll
      for (int df = 0; df < 4; ++df) {
        v4u bu;
        bu[0] = trr[kb * 8 + df * 2][0];
        bu[1] = trr[kb * 8 + df * 2][1];
        bu[2] = trr[kb * 8 + df * 2 + 1][0];
        bu[3] = trr[kb * 8 + df * 2 + 1][1];
        Oacc[df] = __builtin_amdgcn_mfma_f32_32x32x16_f16(
            kb ? pa1 : pa0, __builtin_bit_cast(half8, bu), Oacc[df], 0, 0, 0);
      }

    // ---- B3: publish next tile's staging
    if constexpr (WS) {
      asm volatile("s_waitcnt vmcnt(0)" ::: "memory");
      barrier_plain();
    } else {
      STAGE_WR(s, &ybuf[(t + 1) & 1][0]);
      LOADY(s, (t + 2) & 63);
      barrier_lgkm();
    }
  }

  // ---- epilogue
  if ((l & 15) == 0) sinvl[4 * w + (l >> 4)] = 1.0f / l_run;
  __syncthreads();
#pragma unroll
  for (int df = 0; df < 4; ++df)
#pragma unroll
    for (int r = 0; r < 16; ++r) {
      const int q_ = (r & 3) + 8 * (r >> 2) + 4 * g2;
      const float inv = sinvl[q_];
      Om[(size_t)(bY + row0 + q_) * Dd + (w * 4 + df) * 32 + l31] =
          Oacc[df][r] * inv;
    }
#undef ISSUE_TR
#undef STAGE_WR
#undef LOADY
#undef DMA_STAGE
}

}  // namespace

extern "C" void kernel_launch(void* const* d_in, const int* in_sizes, int n_in,
                              void* d_out, int out_size, void* d_ws,
                              size_t ws_size, hipStream_t stream) {
  (void)in_sizes; (void)n_in; (void)out_size;
  const float* x = (const float*)d_in[0];
  const float* y = (const float*)d_in[1];
  float* A = (float*)d_out;
  float* Bo = A + (size_t)Bb * Nn * Dd;
  const size_t halfws = (size_t)Bb * Nn * Dd * 2;  // 32 MiB per matrix
  dim3 fg(512), fb(512);
  if (d_ws != nullptr && ws_size >= 2 * halfws) {
    v4u* Xw = (v4u*)d_ws;
    v4u* Yw = (v4u*)((char*)d_ws + halfws);
    hipLaunchKernelGGL(convf16, dim3(2048), dim3(256), 0, stream, x, Xw);
    hipLaunchKernelGGL(convf16, dim3(2048), dim3(256), 0, stream, y, Yw);
    hipLaunchKernelGGL(flash_fwd<1>, fg, fb, 0, stream, x, y, Xw, Yw, A);
    hipLaunchKernelGGL(flash_fwd<1>, fg, fb, 0, stream, y, x, Yw, Xw, Bo);
  } else {
    hipLaunchKernelGGL(flash_fwd<0>, fg, fb, 0, stream, x, y, (const v4u*)x,
                       (const v4u*)y, A);
    hipLaunchKernelGGL(flash_fwd<0>, fg, fb, 0, stream, y, x, (const v4u*)y,
                       (const v4u*)x, Bo);
  }
}

// Round 19
// 536.990 us; speedup vs baseline: 1.2581x; 1.1791x over previous
//
#include <hip/hip_runtime.h>
#include <cstdint>
#include <cstddef>

namespace {

constexpr int Bb = 8;
constexpr int Nn = 2048;
constexpr int Dd = 1024;
constexpr int NT = 64;  // kv tiles of 32

typedef _Float16 half8 __attribute__((ext_vector_type(8)));
typedef float f32x4v __attribute__((ext_vector_type(4)));
typedef float f32x16v __attribute__((ext_vector_type(16)));
typedef unsigned int v2u __attribute__((ext_vector_type(2)));
typedef unsigned int v4u __attribute__((ext_vector_type(4)));

__device__ __forceinline__ float fast_exp2(float x) {
  float r;
  asm("v_exp_f32 %0, %1\n\ts_nop 1" : "=v"(r) : "v"(x));
  return r;
}

// pack two f32 -> one u32 of 2x fp16 (RTZ); src0 -> low 16 bits
__device__ __forceinline__ unsigned cvt2(float a, float b) {
  return __builtin_bit_cast(unsigned, __builtin_amdgcn_cvt_pkrtz(a, b));
}

// quad-lane butterfly reductions via DPP quad_perm (VALU pipe).
__device__ __forceinline__ float quad_max(float v) {
  int a = __builtin_amdgcn_update_dpp(0, __builtin_bit_cast(int, v), 0xB1,
                                      0xF, 0xF, true);
  float m = fmaxf(v, __builtin_bit_cast(float, a));
  int b = __builtin_amdgcn_update_dpp(0, __builtin_bit_cast(int, m), 0x4E,
                                      0xF, 0xF, true);
  return fmaxf(m, __builtin_bit_cast(float, b));
}
__device__ __forceinline__ float quad_add(float v) {
  int a = __builtin_amdgcn_update_dpp(0, __builtin_bit_cast(int, v), 0xB1,
                                      0xF, 0xF, true);
  float s = v + __builtin_bit_cast(float, a);
  int b = __builtin_amdgcn_update_dpp(0, __builtin_bit_cast(int, s), 0x4E,
                                      0xF, 0xF, true);
  return s + __builtin_bit_cast(float, b);
}

__device__ __forceinline__ void barrier_lgkm() {
  asm volatile("s_waitcnt lgkmcnt(0)" ::: "memory");
  __builtin_amdgcn_s_barrier();
  __builtin_amdgcn_sched_barrier(0);
}
__device__ __forceinline__ void barrier_plain() {
  __builtin_amdgcn_s_barrier();
  __builtin_amdgcn_sched_barrier(0);
}

// fp32 -> packed fp16 streams for BOTH matrices in one launch.
__global__ void convf16_both(const float* __restrict__ x,
                             const float* __restrict__ y,
                             v4u* __restrict__ xo, v4u* __restrict__ yo) {
  const int n8 = Bb * Nn * Dd / 8;
  const int half = (int)gridDim.x / 2;
  const bool second = (int)blockIdx.x >= half;
  const float* in = second ? y : x;
  v4u* out = second ? yo : xo;
  const int b0 = second ? ((int)blockIdx.x - half) : (int)blockIdx.x;
  int i = b0 * (int)blockDim.x + (int)threadIdx.x;
  const int stride = half * (int)blockDim.x;
  const f32x4v* in4 = (const f32x4v*)in;
  for (; i < n8; i += stride) {
    f32x4v a = in4[2 * i], b = in4[2 * i + 1];
    v4u p;
    p[0] = cvt2(a[0], a[1]);
    p[1] = cvt2(a[2], a[3]);
    p[2] = cvt2(b[0], b[1]);
    p[3] = cvt2(b[2], b[3]);
    out[i] = p;
  }
}

template <int WS>
__device__ __forceinline__ v4u ld8h(const float* f32p, const v4u* h16p) {
  if constexpr (WS) {
    return *h16p;
  } else {
    f32x4v a = *(const f32x4v*)f32p;
    f32x4v b = *(const f32x4v*)(f32p + 4);
    v4u p;
    p[0] = cvt2(a[0], a[1]);
    p[1] = cvt2(a[2], a[3]);
    p[2] = cvt2(b[0], b[1]);
    p[3] = cvt2(b[2], b[3]);
    return p;
  }
}

// Flash attention fwd (no scale), K == V == Y. 512 threads = 8 waves:
// wave = (kvf in 0..1) x (ds in 0..3, 256-d slice). QB=32, KVB=32.
// Champion body (R11, 277us/dispatch measured). Grid = 1024 blocks:
// bid < 512  -> A    = attn(Q=x, Y=y)
// bid >= 512 -> Bout = attn(Q=y, Y=x)
// (bid & 511) preserves the old batch/XCD mapping since 512 % 8 == 0.
template <int WS>
__global__ __launch_bounds__(512, 2) void flash_fwd(
    const float* __restrict__ Xf, const float* __restrict__ Yf,
    const v4u* __restrict__ Xw, const v4u* __restrict__ Yw,
    float* __restrict__ Am, float* __restrict__ Bm) {
  // ybuf tr-window layout:
  // addr(kv,d) = (kv>>2)*8192 + (d>>4)*128 + (kv&3)*32 + (d&15)*2
  __shared__ __attribute__((aligned(128))) char ybuf[65536];
  // pscr2[ds][q][kv] f32, kv-row padded 32->36
  __shared__ __attribute__((aligned(16))) float pscr2[4][32][36];
  __shared__ __attribute__((aligned(16))) char Pb[2048];  // [oct][q] 16B
  __shared__ float sscale[32];
  __shared__ float sinvl[32];
  __shared__ int sflag[2];

  const int tid = (int)threadIdx.x;
  const int w = tid >> 6, l = tid & 63;
  const int lm = l & 15, g = (l >> 4) & 3, g2 = (l >> 5) & 1, l31 = l & 31;
  const int kvf = w >> 2, ds = w & 3;
  const int bigbid = (int)blockIdx.x;
  const int second = bigbid >> 9;  // 0: A op, 1: Bout op
  const int bid = bigbid & 511;
  const int batch = bid & 7, row0 = (bid >> 3) * 32;
  const size_t bY = (size_t)batch * Nn;

  const float* Qf = second ? Yf : Xf;
  const float* Yff = second ? Xf : Yf;
  const v4u* Qw = second ? Yw : Xw;
  const v4u* Yww = second ? Xw : Yw;
  float* Om = second ? Bm : Am;

  // ---- Q fragments (B-operand): lane(lm,g): q = qh*16+lm,
  // d = ds*256 + ks*32 + g*8 + i   (ks = 0..7)
  v4u qreg[2][8];
#pragma unroll
  for (int qh = 0; qh < 2; ++qh)
#pragma unroll
    for (int ks = 0; ks < 8; ++ks) {
      const int rr = row0 + qh * 16 + lm;
      const int dd_ = ds * 256 + ks * 32 + g * 8;
      qreg[qh][ks] = ld8h<WS>(Qf + (size_t)(bY + rr) * Dd + dd_,
                              Qw + (size_t)(bY + rr) * 128 + (dd_ >> 3));
    }

#define LOADY(dst, t_)                                                        \
  do {                                                                        \
    const int rr_ = (t_)*32 + kvf * 16 + lm;                                  \
    _Pragma("unroll") for (int ks = 0; ks < 8; ++ks) {                        \
      const int dd_ = ds * 256 + ks * 32 + g * 8;                             \
      dst[ks] = ld8h<WS>(Yff + (size_t)(bY + rr_) * Dd + dd_,                 \
                         Yww + (size_t)(bY + rr_) * 128 + (dd_ >> 3));        \
    }                                                                         \
  } while (0)

  // staging write: lane(lm,g) kv=kvf*16+lm, d=ds*256+ks*32+g*8 (16B half-row)
  const unsigned sbase =
      (unsigned)((kvf * 4 + (lm >> 2)) * 8192 + (ds * 16 + (g >> 1)) * 128 +
                 (lm & 3) * 32 + (g & 1) * 16);
#define STAGE_WR(SRC)                                                         \
  do {                                                                        \
    _Pragma("unroll") for (int ks = 0; ks < 8; ++ks)                          \
        *(v4u*)(ybuf + sbase + ks * 256) = SRC[ks];                           \
  } while (0)

  v4u s[8];
  LOADY(s, 0);
  STAGE_WR(s);

  f32x16v Oacc[4];
#pragma unroll
  for (int i = 0; i < 4; ++i)
#pragma unroll
    for (int j = 0; j < 16; ++j) Oacc[i][j] = 0.0f;

  float m_run = -__builtin_inff();
  float l_run = 0.0f;
  const unsigned ylds = (unsigned)(uintptr_t)&ybuf[0];
  constexpr float L2E = 1.44269504088896f;

  v2u trr[16];

#define ISSUE_TR()                                                            \
  do {                                                                        \
    _Pragma("unroll") for (int kb = 0; kb < 2; ++kb)                          \
        _Pragma("unroll") for (int df = 0; df < 4; ++df) {                    \
      const unsigned wb =                                                     \
          ylds + (unsigned)((kb * 4 + g2 * 2) * 8192 +                        \
                            ((w * 4 + df) * 2 + (l31 >> 4)) * 128 +           \
                            (l31 & 15) * 8);                                  \
      asm volatile("ds_read_b64_tr_b16 %0, %1"                                \
                   : "=v"(trr[kb * 8 + df * 2])                               \
                   : "v"(wb));                                                \
      asm volatile("ds_read_b64_tr_b16 %0, %1"                                \
                   : "=v"(trr[kb * 8 + df * 2 + 1])                           \
                   : "v"(wb + 8192u));                                        \
    }                                                                         \
  } while (0)

  __syncthreads();

#define TILE_BODY(t_)                                                         \
  do {                                                                        \
    f32x4v acc0 = {0.f, 0.f, 0.f, 0.f}, acc1 = {0.f, 0.f, 0.f, 0.f};          \
    _Pragma("unroll") for (int ks = 0; ks < 8; ++ks) {                        \
      half8 av = __builtin_bit_cast(half8, s[ks]);                            \
      acc0 = __builtin_amdgcn_mfma_f32_16x16x32_f16(                          \
          av, __builtin_bit_cast(half8, qreg[0][ks]), acc0, 0, 0, 0);         \
      acc1 = __builtin_amdgcn_mfma_f32_16x16x32_f16(                          \
          av, __builtin_bit_cast(half8, qreg[1][ks]), acc1, 0, 0, 0);         \
    }                                                                         \
    LOADY(s, ((t_) + 1) & 63);                                                \
    *(f32x4v*)&pscr2[ds][lm][kvf * 16 + g * 4] = acc0;                        \
    *(f32x4v*)&pscr2[ds][16 + lm][kvf * 16 + g * 4] = acc1;                   \
    barrier_lgkm(); /* B1: partials + ybuf(t) visible */                      \
    if (w >= 2) {                                                             \
      ISSUE_TR();                                                             \
    } else {                                                                  \
      __builtin_amdgcn_s_setprio(1);                                          \
      const int rq = w * 16 + (l >> 2); /* global q row */                    \
      const int c = l & 3;              /* kv octet */                        \
      f32x4v lo = {0.f, 0.f, 0.f, 0.f}, hi = {0.f, 0.f, 0.f, 0.f};            \
      _Pragma("unroll") for (int s_ = 0; s_ < 4; ++s_) {                      \
        lo += *(const f32x4v*)&pscr2[s_][rq][c * 8];                          \
        hi += *(const f32x4v*)&pscr2[s_][rq][c * 8 + 4];                      \
      }                                                                       \
      float pm = fmaxf(fmaxf(fmaxf(lo[0], lo[1]), fmaxf(lo[2], lo[3])),       \
                       fmaxf(fmaxf(hi[0], hi[1]), fmaxf(hi[2], hi[3])));      \
      pm = quad_max(pm);                                                      \
      bool defer = (pm <= m_run + 8.0f);                                      \
      bool allw = (bool)__all((int)defer);                                    \
      float scale = 1.0f;                                                     \
      if (!allw) {                                                            \
        float mn = fmaxf(m_run, pm);                                          \
        scale = fast_exp2((m_run - mn) * L2E);                                \
        m_run = mn;                                                           \
      }                                                                       \
      f32x4v ea, eb;                                                          \
      _Pragma("unroll") for (int i = 0; i < 4; ++i) {                         \
        ea[i] = fast_exp2((lo[i] - m_run) * L2E);                             \
        eb[i] = fast_exp2((hi[i] - m_run) * L2E);                             \
      }                                                                       \
      float ps = (ea[0] + ea[1]) + (ea[2] + ea[3]) + (eb[0] + eb[1]) +        \
                 (eb[2] + eb[3]);                                             \
      ps = quad_add(ps);                                                      \
      l_run = l_run * scale + ps;                                             \
      v4u pk;                                                                 \
      pk[0] = cvt2(ea[0], ea[1]);                                             \
      pk[1] = cvt2(ea[2], ea[3]);                                             \
      pk[2] = cvt2(eb[0], eb[1]);                                             \
      pk[3] = cvt2(eb[2], eb[3]);                                             \
      *(v4u*)(Pb + c * 512 + rq * 16) = pk;                                   \
      if (c == 0) sscale[rq] = scale;                                         \
      if (l == 0) sflag[w] = allw ? 0 : 1;                                    \
      __builtin_amdgcn_s_setprio(0);                                          \
      ISSUE_TR();                                                             \
    }                                                                         \
    barrier_lgkm(); /* B2: P + stats visible; tr data in regs */              \
    half8 pa0 = *(const half8*)(Pb + g2 * 512 + l31 * 16);                    \
    half8 pa1 = *(const half8*)(Pb + (2 + g2) * 512 + l31 * 16);              \
    if (sflag[0] | sflag[1]) {                                                \
      _Pragma("unroll") for (int df = 0; df < 4; ++df)                        \
          _Pragma("unroll") for (int r = 0; r < 16; ++r) {                    \
        const int q_ = (r & 3) + 8 * (r >> 2) + 4 * g2;                       \
        Oacc[df][r] *= sscale[q_];                                            \
      }                                                                       \
    }                                                                         \
    asm volatile("s_waitcnt lgkmcnt(0)" ::: "memory");                        \
    __builtin_amdgcn_sched_barrier(0);                                        \
    _Pragma("unroll") for (int kb = 0; kb < 2; ++kb)                          \
        _Pragma("unroll") for (int df = 0; df < 4; ++df) {                    \
      v4u bu;                                                                 \
      bu[0] = trr[kb * 8 + df * 2][0];                                        \
      bu[1] = trr[kb * 8 + df * 2][1];                                        \
      bu[2] = trr[kb * 8 + df * 2 + 1][0];                                    \
      bu[3] = trr[kb * 8 + df * 2 + 1][1];                                    \
      Oacc[df] = __builtin_amdgcn_mfma_f32_32x32x16_f16(                      \
          kb ? pa1 : pa0, __builtin_bit_cast(half8, bu), Oacc[df], 0, 0, 0);  \
    }                                                                         \
    barrier_plain(); /* B3: PV/pscr/Pb reads done, ybuf free */               \
    STAGE_WR(s);                                                              \
  } while (0)

  for (int t = 0; t < NT; ++t) {
    TILE_BODY(t);
  }

  // ---- epilogue
  if (w < 2 && (l & 3) == 0) sinvl[w * 16 + (l >> 2)] = 1.0f / l_run;
  __syncthreads();
#pragma unroll
  for (int df = 0; df < 4; ++df)
#pragma unroll
    for (int r = 0; r < 16; ++r) {
      const int q_ = (r & 3) + 8 * (r >> 2) + 4 * g2;
      const float inv = sinvl[q_];
      Om[(size_t)(bY + row0 + q_) * Dd + (w * 4 + df) * 32 + l31] =
          Oacc[df][r] * inv;
    }
#undef TILE_BODY
#undef ISSUE_TR
#undef STAGE_WR
#undef LOADY
}

}  // namespace

extern "C" void kernel_launch(void* const* d_in, const int* in_sizes, int n_in,
                              void* d_out, int out_size, void* d_ws,
                              size_t ws_size, hipStream_t stream) {
  (void)in_sizes; (void)n_in; (void)out_size;
  const float* x = (const float*)d_in[0];
  const float* y = (const float*)d_in[1];
  float* A = (float*)d_out;
  float* Bo = A + (size_t)Bb * Nn * Dd;
  const size_t halfws = (size_t)Bb * Nn * Dd * 2;  // 32 MiB per matrix
  dim3 fg(1024), fb(512);
  if (d_ws != nullptr && ws_size >= 2 * halfws) {
    v4u* Xw = (v4u*)d_ws;
    v4u* Yw = (v4u*)((char*)d_ws + halfws);
    hipLaunchKernelGGL(convf16_both, dim3(4096), dim3(256), 0, stream, x, y,
                       Xw, Yw);
    hipLaunchKernelGGL(flash_fwd<1>, fg, fb, 0, stream, x, y, Xw, Yw, A, Bo);
  } else {
    hipLaunchKernelGGL(flash_fwd<0>, fg, fb, 0, stream, x, y, (const v4u*)x,
                       (const v4u*)y, A, Bo);
  }
}